// Round 1
// baseline (804.116 us; speedup 1.0000x reference)
//
#include <hip/hip_runtime.h>
#include <math.h>

// FutureFutureCrossAttention — MI355X f32 implementation, round 0 (correctness-first).
// Shapes: B=8 A=64 K=16 L=30 D=M=128 H=8 hd=16.
// Restructure: project future_feat ONCE (15360 rows) for Q/K/V, gather at attention
// time (reference projects gathered neighbours = 16x more GEMM work).

#define NB 8
#define NA 64
#define NK 16
#define NL 30
#define ND 128
#define NM 128
#define NH 8
#define NHD 16
#define NKK (NK*NL)          // 480
#define FSCALE 0.25f         // 16^-0.5
#define NROWS (NB*NA*NL)     // 15360

// ---------------------------------------------------------------------------
// Mask dtype detection: neighbour_mask is bool in the reference; the harness may
// upload it as int32, float32 or raw bytes. Scan first 8KB (safe under every
// interpretation) and classify. flag: 0=int32{0,1}, 1=f32{0.0,1.0}, 2=bytes.
__global__ void detect_mask_fmt(const unsigned int* __restrict__ m, int* __restrict__ flag)
{
    __shared__ int not_i32, not_f32;
    if (threadIdx.x == 0) { not_i32 = 0; not_f32 = 0; }
    __syncthreads();
    for (int i = threadIdx.x; i < 2048; i += 256) {
        unsigned int u = m[i];
        if (u > 1u) not_i32 = 1;                       // benign race, all write 1
        if (u != 0u && u != 0x3F800000u) not_f32 = 1;
    }
    __syncthreads();
    if (threadIdx.x == 0) *flag = (!not_i32) ? 0 : ((!not_f32) ? 1 : 2);
}

// ---------------------------------------------------------------------------
// Fused Q/K/V projection: one block per (b,a); x tile [30][128] in LDS; thread
// (j = tid&127, rh = tid>>7) computes 15 rows x 1 col for each of the 3 matrices.
__global__ __launch_bounds__(256) void proj_qkv(
    const float* __restrict__ x,
    const float* __restrict__ Wq, const float* __restrict__ bq,
    const float* __restrict__ Wk, const float* __restrict__ bk,
    const float* __restrict__ Wv, const float* __restrict__ bv,
    float* __restrict__ qp, float* __restrict__ kp, float* __restrict__ vp)
{
    __shared__ __align__(16) float xs[NL][ND];   // 15360 B
    const int ba = blockIdx.x;
    const float* xrow = x + (size_t)ba * NL * ND;
    for (int i = threadIdx.x; i < NL*ND/4; i += 256)
        ((float4*)xs)[i] = ((const float4*)xrow)[i];
    __syncthreads();

    const int j  = threadIdx.x & 127;
    const int rh = threadIdx.x >> 7;     // 0: rows 0..14, 1: rows 15..29
    const float* Ws[3] = {Wq, Wk, Wv};
    const float* bs[3] = {bq, bk, bv};
    float*       Os[3] = {qp, kp, vp};

    #pragma unroll
    for (int m = 0; m < 3; ++m) {
        const float* W = Ws[m];
        float acc[15];
        #pragma unroll
        for (int r = 0; r < 15; ++r) acc[r] = 0.f;
        for (int d = 0; d < ND; d += 4) {
            float w0 = W[(d+0)*NM + j];
            float w1 = W[(d+1)*NM + j];
            float w2 = W[(d+2)*NM + j];
            float w3 = W[(d+3)*NM + j];
            #pragma unroll
            for (int r = 0; r < 15; ++r) {
                float4 xv = *(const float4*)&xs[rh*15 + r][d];  // LDS broadcast
                acc[r] = fmaf(xv.x, w0, acc[r]);
                acc[r] = fmaf(xv.y, w1, acc[r]);
                acc[r] = fmaf(xv.z, w2, acc[r]);
                acc[r] = fmaf(xv.w, w3, acc[r]);
            }
        }
        float bj = bs[m][j];
        float* O = Os[m] + ((size_t)ba*NL + rh*15)*NM + j;
        #pragma unroll
        for (int r = 0; r < 15; ++r) O[r*NM] = acc[r] + bj;
    }
}

// ---------------------------------------------------------------------------
// Attention: one block per (ba, h). Thread t owns score columns kk0=t, kk1=256+t
// (kk = k*30 + l), scores held in 60 VGPRs. Softmax = shuffle + cross-wave LDS
// reduce. PV via LDS round-trip of P in two q-halves (s_buf padded to 481 cols).
__global__ __launch_bounds__(256) void attn_kernel(
    const float* __restrict__ qp, const float* __restrict__ kp, const float* __restrict__ vp,
    const float* __restrict__ geom_bias, const int* __restrict__ nidx,
    const void* __restrict__ nmask, const int* __restrict__ mask_fmt,
    float* __restrict__ attn_out, float* __restrict__ ctx_out)
{
    __shared__ __align__(16) float v_s[NKK][16];    // 30720 B
    __shared__ __align__(16) float s_buf[15][481];  // 28860 B (also reused as float4 partials)
    __shared__ __align__(16) float q_s[NL][16];     // 1920 B (pre-scaled)
    __shared__ float biasm[NK];
    __shared__ int   idx_s[NK];
    __shared__ float wred[4][NL];
    __shared__ float mfin[NL];
    __shared__ float ifin[NL];

    const int t   = threadIdx.x;
    const int blk = blockIdx.x;           // = ba*NH + h
    const int h   = blk & (NH-1);
    const int ba  = blk >> 3;
    const int b   = ba >> 6;              // A = 64

    if (t < NK) {
        idx_s[t] = nidx[ba*NK + t];
        const int fmt = *mask_fmt;
        bool mv;
        if (fmt == 0)      mv = ((const int*)nmask)[ba*NK + t] != 0;
        else if (fmt == 1) mv = ((const float*)nmask)[ba*NK + t] != 0.0f;
        else               mv = ((const unsigned char*)nmask)[ba*NK + t] != 0;
        biasm[t] = mv ? geom_bias[ba*NK + t] : -INFINITY;
    }
    for (int i = t; i < NL*4; i += 256) {
        int q = i >> 2, p = i & 3;
        float4 qv = *(const float4*)(qp + ((size_t)ba*NL + q)*NM + h*NHD + p*4);
        qv.x *= FSCALE; qv.y *= FSCALE; qv.z *= FSCALE; qv.w *= FSCALE;
        *(float4*)&q_s[q][p*4] = qv;
    }
    __syncthreads();   // idx_s/biasm/q_s visible

    // stage gathered V into LDS
    for (int i = t; i < NKK*4; i += 256) {
        int kk = i >> 2, p = i & 3;
        int kn = kk / NL, l = kk - kn*NL;
        *(float4*)&v_s[kk][p*4] =
            *(const float4*)(vp + ((size_t)(b*NA + idx_s[kn])*NL + l)*NM + h*NHD + p*4);
    }

    // K fragments straight to registers (no LDS needed for K)
    const int  kk0  = t;
    const int  kk1  = 256 + t;
    const bool has1 = (t < NKK - 256);    // t < 224
    const int k0 = kk0 / NL, l0 = kk0 - k0*NL;
    const float* kb0 = kp + ((size_t)(b*NA + idx_s[k0])*NL + l0)*NM + h*NHD;
    float4 k0a = *(const float4*)(kb0 + 0);
    float4 k0b = *(const float4*)(kb0 + 4);
    float4 k0c = *(const float4*)(kb0 + 8);
    float4 k0d = *(const float4*)(kb0 + 12);
    float  bb0 = biasm[k0];
    float4 k1a = make_float4(0,0,0,0), k1b = k1a, k1c = k1a, k1d = k1a;
    float  bb1 = 0.f;
    if (has1) {
        const int k1 = kk1 / NL, l1 = kk1 - k1*NL;
        const float* kb1 = kp + ((size_t)(b*NA + idx_s[k1])*NL + l1)*NM + h*NHD;
        k1a = *(const float4*)(kb1 + 0);
        k1b = *(const float4*)(kb1 + 4);
        k1c = *(const float4*)(kb1 + 8);
        k1d = *(const float4*)(kb1 + 12);
        bb1 = biasm[k1];
    }

    // scores for both owned columns, all 30 q rows, in registers
    float s0[NL], s1[NL];
    #pragma unroll
    for (int q = 0; q < NL; ++q) {
        float4 qa = *(const float4*)&q_s[q][0];
        float4 qb = *(const float4*)&q_s[q][4];
        float4 qc = *(const float4*)&q_s[q][8];
        float4 qd = *(const float4*)&q_s[q][12];
        float d0 = qa.x*k0a.x + qa.y*k0a.y + qa.z*k0a.z + qa.w*k0a.w
                 + qb.x*k0b.x + qb.y*k0b.y + qb.z*k0b.z + qb.w*k0b.w
                 + qc.x*k0c.x + qc.y*k0c.y + qc.z*k0c.z + qc.w*k0c.w
                 + qd.x*k0d.x + qd.y*k0d.y + qd.z*k0d.z + qd.w*k0d.w;
        s0[q] = d0 + bb0;
        float d1 = qa.x*k1a.x + qa.y*k1a.y + qa.z*k1a.z + qa.w*k1a.w
                 + qb.x*k1b.x + qb.y*k1b.y + qb.z*k1b.z + qb.w*k1b.w
                 + qc.x*k1c.x + qc.y*k1c.y + qc.z*k1c.z + qc.w*k1c.w
                 + qd.x*k1d.x + qd.y*k1d.y + qd.z*k1d.z + qd.w*k1d.w;
        s1[q] = has1 ? (d1 + bb1) : -INFINITY;
    }

    const int lane = t & 63, wid = t >> 6;

    // row max over kk (across all threads)
    #pragma unroll
    for (int q = 0; q < NL; ++q) {
        float m = fmaxf(s0[q], s1[q]);
        #pragma unroll
        for (int off = 32; off > 0; off >>= 1) m = fmaxf(m, __shfl_down(m, off));
        if (lane == 0) wred[wid][q] = m;
    }
    __syncthreads();
    if (t < NL) {
        mfin[t] = fmaxf(fmaxf(wred[0][t], wred[1][t]), fmaxf(wred[2][t], wred[3][t]));
    }
    __syncthreads();

    #pragma unroll
    for (int q = 0; q < NL; ++q) {
        float mq = mfin[q];
        bool ok = (mq > -INFINITY);               // all-masked row -> attn = 0 (nan_to_num)
        s0[q] = ok ? __expf(s0[q] - mq) : 0.f;
        s1[q] = (ok && has1) ? __expf(s1[q] - mq) : 0.f;
    }

    // row sum
    #pragma unroll
    for (int q = 0; q < NL; ++q) {
        float s = s0[q] + s1[q];
        #pragma unroll
        for (int off = 32; off > 0; off >>= 1) s += __shfl_down(s, off);
        if (lane == 0) wred[wid][q] = s;
    }
    __syncthreads();
    if (t < NL) {
        float s = wred[0][t] + wred[1][t] + wred[2][t] + wred[3][t];
        ifin[t] = (s > 0.f) ? 1.f/s : 0.f;
    }
    __syncthreads();

    // normalize in regs, write attn output (coalesced along kk)
    const size_t abase = (size_t)blk * NL * NKK;
    #pragma unroll
    for (int q = 0; q < NL; ++q) {
        float inv = ifin[q];
        s0[q] *= inv;
        s1[q] *= inv;
        attn_out[abase + (size_t)q*NKK + kk0] = s0[q];
        if (has1) attn_out[abase + (size_t)q*NKK + kk1] = s1[q];
    }

    // PV: two q-halves through s_buf. Wave c handles kk ≡ c (mod 4); lane -> (qh,d4).
    const int c  = wid;
    const int qh = lane >> 2;    // 0..15 (15 = idle)
    const int d4 = lane & 3;
    float4* part = (float4*)&s_buf[0][0];

    #pragma unroll
    for (int half = 0; half < 2; ++half) {
        const int qb = half * 15;
        __syncthreads();                       // prior s_buf users done
        #pragma unroll
        for (int qq = 0; qq < 15; ++qq) {
            s_buf[qq][kk0] = s0[qb + qq];
            if (has1) s_buf[qq][kk1] = s1[qb + qq];
        }
        __syncthreads();                       // P visible
        float4 acc = make_float4(0,0,0,0);
        if (qh < 15) {
            #pragma unroll 4
            for (int i = 0; i < NKK/4; ++i) {
                int kk = 4*i + c;
                float a = s_buf[qh][kk];       // 15 rows, pad 481 -> conflict-free
                float4 vv = *(const float4*)&v_s[kk][d4*4];   // broadcast across qh
                acc.x = fmaf(a, vv.x, acc.x);
                acc.y = fmaf(a, vv.y, acc.y);
                acc.z = fmaf(a, vv.z, acc.z);
                acc.w = fmaf(a, vv.w, acc.w);
            }
        }
        __syncthreads();                       // s_buf reads done, safe to reuse as partials
        if (qh < 15) part[c*60 + qh*4 + d4] = acc;
        __syncthreads();
        if (t < 60) {
            int q2 = t >> 2, dd = t & 3;
            float4 p0 = part[  0 + q2*4 + dd];
            float4 p1 = part[ 60 + q2*4 + dd];
            float4 p2 = part[120 + q2*4 + dd];
            float4 p3 = part[180 + q2*4 + dd];
            float4 s;
            s.x = (p0.x + p1.x) + (p2.x + p3.x);
            s.y = (p0.y + p1.y) + (p2.y + p3.y);
            s.z = (p0.z + p1.z) + (p2.z + p3.z);
            s.w = (p0.w + p1.w) + (p2.w + p3.w);
            *(float4*)(ctx_out + ((size_t)ba*NL + qb + q2)*NM + h*NHD + dd*4) = s;
        }
    }
}

// ---------------------------------------------------------------------------
// Output projection: ctx aliases the `out` region of d_out. Each block stages its
// ctx tile into LDS BEFORE overwriting those same rows -> in-place is safe.
__global__ __launch_bounds__(256) void out_proj(
    const float* __restrict__ ctx, const float* __restrict__ Wo,
    const float* __restrict__ bo, float* __restrict__ out)
{
    __shared__ __align__(16) float xs[NL][ND];
    const int ba = blockIdx.x;
    const float* xrow = ctx + (size_t)ba * NL * ND;
    for (int i = threadIdx.x; i < NL*ND/4; i += 256)
        ((float4*)xs)[i] = ((const float4*)xrow)[i];
    __syncthreads();

    const int j  = threadIdx.x & 127;
    const int rh = threadIdx.x >> 7;
    float acc[15];
    #pragma unroll
    for (int r = 0; r < 15; ++r) acc[r] = 0.f;
    for (int d = 0; d < ND; d += 4) {
        float w0 = Wo[(d+0)*NM + j];
        float w1 = Wo[(d+1)*NM + j];
        float w2 = Wo[(d+2)*NM + j];
        float w3 = Wo[(d+3)*NM + j];
        #pragma unroll
        for (int r = 0; r < 15; ++r) {
            float4 xv = *(const float4*)&xs[rh*15 + r][d];
            acc[r] = fmaf(xv.x, w0, acc[r]);
            acc[r] = fmaf(xv.y, w1, acc[r]);
            acc[r] = fmaf(xv.z, w2, acc[r]);
            acc[r] = fmaf(xv.w, w3, acc[r]);
        }
    }
    float bj = bo[j];
    float* O = out + ((size_t)ba*NL + rh*15)*NM + j;
    #pragma unroll
    for (int r = 0; r < 15; ++r) O[r*NM] = acc[r] + bj;
}

// ---------------------------------------------------------------------------
extern "C" void kernel_launch(void* const* d_in, const int* in_sizes, int n_in,
                              void* d_out, int out_size, void* d_ws, size_t ws_size,
                              hipStream_t stream)
{
    const float* x    = (const float*)d_in[0];
    const float* gb   = (const float*)d_in[1];
    const float* Wq   = (const float*)d_in[2];
    const float* bq   = (const float*)d_in[3];
    const float* Wk   = (const float*)d_in[4];
    const float* bk   = (const float*)d_in[5];
    const float* Wv   = (const float*)d_in[6];
    const float* bv   = (const float*)d_in[7];
    const float* Wo   = (const float*)d_in[8];
    const float* bo   = (const float*)d_in[9];
    const int*   nidx = (const int*)d_in[10];
    const void*  nmask= d_in[11];

    float* out  = (float*)d_out;                       // [15360, 128]
    float* attn = out + (size_t)NROWS * NM;            // [B,A,H,L,K,L] flat

    // workspace: qp, kp, vp (each 15360*128 f32 = 7.86 MB) + mask-format flag.
    float* qp = (float*)d_ws;
    float* kp = qp + (size_t)NROWS * NM;
    float* vp = kp + (size_t)NROWS * NM;
    int* mflag = (int*)(vp + (size_t)NROWS * NM);

    detect_mask_fmt<<<1, 256, 0, stream>>>((const unsigned int*)nmask, mflag);
    proj_qkv<<<NB*NA, 256, 0, stream>>>(x, Wq, bq, Wk, bk, Wv, bv, qp, kp, vp);
    attn_kernel<<<NB*NA*NH, 256, 0, stream>>>(qp, kp, vp, gb, nidx, nmask, mflag,
                                              attn, /*ctx aliases out*/ out);
    out_proj<<<NB*NA, 256, 0, stream>>>(out, Wo, bo, out);
}

// Round 2
// 389.574 us; speedup vs baseline: 2.0641x; 2.0641x over previous
//
#include <hip/hip_runtime.h>
#include <math.h>

// FutureFutureCrossAttention — MI355X, round 2: MFMA attention.
// Shapes: B=8 A=64 K=16 L=30 D=M=128 H=8 hd=16.
// attn_kernel rewritten around mfma_f32_16x16x32_bf16:
//   QK^T: A = Q split hi/lo bf16 (2 MFMAs, score err ~2e-3), B = gathered K single bf16.
//   PV:   A = P single bf16 via wave-private LDS chunk buffer, B = V^T single bf16.
// Verified fragment layouts (learn_hip m89): A[m=lane&15][k=quad*8+j],
// C/D col=lane&15, row=quad*4+reg.

#define NB 8
#define NA 64
#define NK 16
#define NL 30
#define ND 128
#define NM 128
#define NH 8
#define NHD 16
#define NKK (NK*NL)          // 480
#define FSCALE 0.25f         // 16^-0.5
#define NROWS (NB*NA*NL)     // 15360

typedef __attribute__((ext_vector_type(8))) short bf16x8;
typedef __attribute__((ext_vector_type(4))) float f32x4;

__device__ __forceinline__ unsigned short bf16r(float x) {
    unsigned u = __float_as_uint(x);
    return (unsigned short)((u + 0x7fffu + ((u >> 16) & 1u)) >> 16);
}

// ---------------------------------------------------------------------------
// Mask dtype detection (bool may arrive as int32 / f32 / bytes).
__global__ void detect_mask_fmt(const unsigned int* __restrict__ m, int* __restrict__ flag)
{
    __shared__ int not_i32, not_f32;
    if (threadIdx.x == 0) { not_i32 = 0; not_f32 = 0; }
    __syncthreads();
    for (int i = threadIdx.x; i < 2048; i += 256) {
        unsigned int u = m[i];
        if (u > 1u) not_i32 = 1;
        if (u != 0u && u != 0x3F800000u) not_f32 = 1;
    }
    __syncthreads();
    if (threadIdx.x == 0) *flag = (!not_i32) ? 0 : ((!not_f32) ? 1 : 2);
}

// ---------------------------------------------------------------------------
// Fused Q/K/V projection (unchanged from round 1 — revisit per counters).
__global__ __launch_bounds__(256) void proj_qkv(
    const float* __restrict__ x,
    const float* __restrict__ Wq, const float* __restrict__ bq,
    const float* __restrict__ Wk, const float* __restrict__ bk,
    const float* __restrict__ Wv, const float* __restrict__ bv,
    float* __restrict__ qp, float* __restrict__ kp, float* __restrict__ vp)
{
    __shared__ __align__(16) float xs[NL][ND];
    const int ba = blockIdx.x;
    const float* xrow = x + (size_t)ba * NL * ND;
    for (int i = threadIdx.x; i < NL*ND/4; i += 256)
        ((float4*)xs)[i] = ((const float4*)xrow)[i];
    __syncthreads();

    const int j  = threadIdx.x & 127;
    const int rh = threadIdx.x >> 7;
    const float* Ws[3] = {Wq, Wk, Wv};
    const float* bs[3] = {bq, bk, bv};
    float*       Os[3] = {qp, kp, vp};

    #pragma unroll
    for (int m = 0; m < 3; ++m) {
        const float* W = Ws[m];
        float acc[15];
        #pragma unroll
        for (int r = 0; r < 15; ++r) acc[r] = 0.f;
        for (int d = 0; d < ND; d += 4) {
            float w0 = W[(d+0)*NM + j];
            float w1 = W[(d+1)*NM + j];
            float w2 = W[(d+2)*NM + j];
            float w3 = W[(d+3)*NM + j];
            #pragma unroll
            for (int r = 0; r < 15; ++r) {
                float4 xv = *(const float4*)&xs[rh*15 + r][d];
                acc[r] = fmaf(xv.x, w0, acc[r]);
                acc[r] = fmaf(xv.y, w1, acc[r]);
                acc[r] = fmaf(xv.z, w2, acc[r]);
                acc[r] = fmaf(xv.w, w3, acc[r]);
            }
        }
        float bj = bs[m][j];
        float* O = Os[m] + ((size_t)ba*NL + rh*15)*NM + j;
        #pragma unroll
        for (int r = 0; r < 15; ++r) O[r*NM] = acc[r] + bj;
    }
}

// ---------------------------------------------------------------------------
// MFMA attention. Block = (ba, h), 128 threads = 2 waves; wave w owns q rows
// w*16 .. w*16+15 (rows 30,31 are zero-padded, stores masked).
__global__ __launch_bounds__(128, 2) void attn_kernel(
    const float* __restrict__ qp, const float* __restrict__ kp, const float* __restrict__ vp,
    const float* __restrict__ geom_bias, const int* __restrict__ nidx,
    const void* __restrict__ nmask, const int* __restrict__ mask_fmt,
    float* __restrict__ attn_out, float* __restrict__ ctx_out)
{
    __shared__ __align__(16) short Kbf[NKK][16];   // gathered K, bf16 [kk][hd]  15360 B
    __shared__ __align__(16) short Vt[16][488];    // gathered V^T bf16 [hd][kk] 15616 B (stride 488: 61 16B-units, odd -> conflict-free b128)
    __shared__ __align__(16) short pbuf[2][16][40];// per-wave P chunk [q][32kk]+pad 2560 B
    __shared__ float bias_ext[NKK];                // bias-or(-inf) per kk        1920 B
    __shared__ float biasm[NK];
    __shared__ int   idx_s[NK];

    const int t    = threadIdx.x;
    const int blk  = blockIdx.x;          // ba*8 + h
    const int h    = blk & 7;
    const int ba   = blk >> 3;
    const int b    = ba >> 6;             // A = 64
    const int lane = t & 63;
    const int w    = t >> 6;              // wave id = q-tile id
    const int n    = lane & 15;
    const int quad = lane >> 4;

    if (t < NK) {
        idx_s[t] = nidx[ba*NK + t];
        const int fmt = *mask_fmt;
        bool mv;
        if (fmt == 0)      mv = ((const int*)nmask)[ba*NK + t] != 0;
        else if (fmt == 1) mv = ((const float*)nmask)[ba*NK + t] != 0.0f;
        else               mv = ((const unsigned char*)nmask)[ba*NK + t] != 0;
        biasm[t] = mv ? geom_bias[ba*NK + t] : -INFINITY;
    }
    __syncthreads();   // idx_s / biasm ready

    // ---- stage gathered K (bf16) and V^T (bf16) into LDS, fill bias_ext ----
    for (int i = t; i < NKK*4; i += 128) {
        const int kk = i >> 2, p = i & 3;
        const int kn = kk / NL, l = kk - kn*NL;
        const size_t off = ((size_t)(b*NA + idx_s[kn])*NL + l)*NM + h*NHD + p*4;
        float4 kv = *(const float4*)(kp + off);
        unsigned long long pk =
              (unsigned long long)bf16r(kv.x)
            | ((unsigned long long)bf16r(kv.y) << 16)
            | ((unsigned long long)bf16r(kv.z) << 32)
            | ((unsigned long long)bf16r(kv.w) << 48);
        *(unsigned long long*)&Kbf[kk][p*4] = pk;
        float4 vv = *(const float4*)(vp + off);
        Vt[p*4+0][kk] = (short)bf16r(vv.x);
        Vt[p*4+1][kk] = (short)bf16r(vv.y);
        Vt[p*4+2][kk] = (short)bf16r(vv.z);
        Vt[p*4+3][kk] = (short)bf16r(vv.w);
    }
    for (int i = t; i < NKK; i += 128) bias_ext[i] = biasm[i / NL];

    // ---- Q A-fragments: hi/lo bf16 split, SCALE folded in ----
    bf16x8 a_hi, a_lo;
    #pragma unroll
    for (int j = 0; j < 8; ++j) { a_hi[j] = 0; a_lo[j] = 0; }
    const int qrow = w*16 + n;           // A-operand row m = lane&15
    if (quad < 2 && qrow < NL) {         // k = quad*8+j; real hd only k<16
        const float* qb = qp + ((size_t)ba*NL + qrow)*NM + h*NHD + quad*8;
        float4 x0 = *(const float4*)(qb);
        float4 x1 = *(const float4*)(qb + 4);
        float xv[8] = {x0.x,x0.y,x0.z,x0.w,x1.x,x1.y,x1.z,x1.w};
        #pragma unroll
        for (int j = 0; j < 8; ++j) {
            float x = xv[j] * FSCALE;
            unsigned short hb = bf16r(x);
            a_hi[j] = (short)hb;
            a_lo[j] = (short)bf16r(x - __uint_as_float(((unsigned)hb) << 16));
        }
    }
    __syncthreads();   // Kbf / Vt / bias_ext ready

    // ---- QK^T: 30 tiles of 16 kk; scores in C layout (row=quad*4+r, col=n) ----
    float s[NL][4];
    #pragma unroll
    for (int tt = 0; tt < NL; ++tt) {
        bf16x8 bfrag;
        #pragma unroll
        for (int j = 0; j < 8; ++j) bfrag[j] = 0;
        if (quad < 2)                      // k >= 16 rows of B are zero pad
            bfrag = *(const bf16x8*)&Kbf[tt*16 + n][quad*8];
        f32x4 acc = {0.f, 0.f, 0.f, 0.f};
        acc = __builtin_amdgcn_mfma_f32_16x16x32_bf16(a_hi, bfrag, acc, 0, 0, 0);
        acc = __builtin_amdgcn_mfma_f32_16x16x32_bf16(a_lo, bfrag, acc, 0, 0, 0);
        const float bv = bias_ext[tt*16 + n];
        s[tt][0] = acc[0] + bv;
        s[tt][1] = acc[1] + bv;
        s[tt][2] = acc[2] + bv;
        s[tt][3] = acc[3] + bv;
    }

    // ---- softmax along kk: in-lane over 30 tiles + xor-shuffle over 16 lanes ----
    #pragma unroll
    for (int r = 0; r < 4; ++r) {
        float m = -INFINITY;
        #pragma unroll
        for (int tt = 0; tt < NL; ++tt) m = fmaxf(m, s[tt][r]);
        m = fmaxf(m, __shfl_xor(m, 1));
        m = fmaxf(m, __shfl_xor(m, 2));
        m = fmaxf(m, __shfl_xor(m, 4));
        m = fmaxf(m, __shfl_xor(m, 8));
        const bool ok = (m > -INFINITY);   // all-masked row -> attn = 0 (nan_to_num)
        float sum = 0.f;
        #pragma unroll
        for (int tt = 0; tt < NL; ++tt) {
            float p = ok ? __expf(s[tt][r] - m) : 0.f;
            s[tt][r] = p;
            sum += p;
        }
        sum += __shfl_xor(sum, 1);
        sum += __shfl_xor(sum, 2);
        sum += __shfl_xor(sum, 4);
        sum += __shfl_xor(sum, 8);
        const float inv = (sum > 0.f) ? 1.f / sum : 0.f;
        #pragma unroll
        for (int tt = 0; tt < NL; ++tt) s[tt][r] *= inv;
    }

    // ---- write attn (f32, exact): lane covers col n of tiles, 4 rows ----
    const size_t abase = (size_t)blk * NL * NKK;
    #pragma unroll
    for (int r = 0; r < 4; ++r) {
        const int qr = w*16 + quad*4 + r;
        if (qr < NL) {
            float* ap = attn_out + abase + (size_t)qr * NKK + n;
            #pragma unroll
            for (int tt = 0; tt < NL; ++tt) ap[tt*16] = s[tt][r];
        }
    }

    // ---- PV: per 32-kk chunk, P -> wave-private LDS (bf16) -> A-frag; B = Vt ----
    f32x4 ctx = {0.f, 0.f, 0.f, 0.f};
    #pragma unroll
    for (int c = 0; c < 15; ++c) {
        #pragma unroll
        for (int r = 0; r < 4; ++r) {
            pbuf[w][quad*4 + r][n]      = (short)bf16r(s[2*c    ][r]);
            pbuf[w][quad*4 + r][16 + n] = (short)bf16r(s[2*c + 1][r]);
        }
        // same-wave ds_write -> ds_read: HW instruction order + compiler waitcnt
        bf16x8 pa = *(const bf16x8*)&pbuf[w][n][quad*8];          // A[m=n][k=quad*8+j]
        bf16x8 vb = *(const bf16x8*)&Vt[n][c*32 + quad*8];        // B[k][n=d]
        ctx = __builtin_amdgcn_mfma_f32_16x16x32_bf16(pa, vb, ctx, 0, 0, 0);
    }

    // ---- ctx out: row=quad*4+r (q), col=n (d) ----
    #pragma unroll
    for (int r = 0; r < 4; ++r) {
        const int qr = w*16 + quad*4 + r;
        if (qr < NL)
            ctx_out[((size_t)ba*NL + qr)*NM + h*NHD + n] = ctx[r];
    }
}

// ---------------------------------------------------------------------------
// Output projection: ctx aliases the `out` region of d_out (tile staged to LDS
// before overwrite -> in-place safe).
__global__ __launch_bounds__(256) void out_proj(
    const float* __restrict__ ctx, const float* __restrict__ Wo,
    const float* __restrict__ bo, float* __restrict__ out)
{
    __shared__ __align__(16) float xs[NL][ND];
    const int ba = blockIdx.x;
    const float* xrow = ctx + (size_t)ba * NL * ND;
    for (int i = threadIdx.x; i < NL*ND/4; i += 256)
        ((float4*)xs)[i] = ((const float4*)xrow)[i];
    __syncthreads();

    const int j  = threadIdx.x & 127;
    const int rh = threadIdx.x >> 7;
    float acc[15];
    #pragma unroll
    for (int r = 0; r < 15; ++r) acc[r] = 0.f;
    for (int d = 0; d < ND; d += 4) {
        float w0 = Wo[(d+0)*NM + j];
        float w1 = Wo[(d+1)*NM + j];
        float w2 = Wo[(d+2)*NM + j];
        float w3 = Wo[(d+3)*NM + j];
        #pragma unroll
        for (int r = 0; r < 15; ++r) {
            float4 xv = *(const float4*)&xs[rh*15 + r][d];
            acc[r] = fmaf(xv.x, w0, acc[r]);
            acc[r] = fmaf(xv.y, w1, acc[r]);
            acc[r] = fmaf(xv.z, w2, acc[r]);
            acc[r] = fmaf(xv.w, w3, acc[r]);
        }
    }
    float bj = bo[j];
    float* O = out + ((size_t)ba*NL + rh*15)*NM + j;
    #pragma unroll
    for (int r = 0; r < 15; ++r) O[r*NM] = acc[r] + bj;
}

// ---------------------------------------------------------------------------
extern "C" void kernel_launch(void* const* d_in, const int* in_sizes, int n_in,
                              void* d_out, int out_size, void* d_ws, size_t ws_size,
                              hipStream_t stream)
{
    const float* x    = (const float*)d_in[0];
    const float* gb   = (const float*)d_in[1];
    const float* Wq   = (const float*)d_in[2];
    const float* bq   = (const float*)d_in[3];
    const float* Wk   = (const float*)d_in[4];
    const float* bk   = (const float*)d_in[5];
    const float* Wv   = (const float*)d_in[6];
    const float* bv   = (const float*)d_in[7];
    const float* Wo   = (const float*)d_in[8];
    const float* bo   = (const float*)d_in[9];
    const int*   nidx = (const int*)d_in[10];
    const void*  nmask= d_in[11];

    float* out  = (float*)d_out;                       // [15360, 128]
    float* attn = out + (size_t)NROWS * NM;            // [B,A,H,L,K,L] flat

    float* qp = (float*)d_ws;
    float* kp = qp + (size_t)NROWS * NM;
    float* vp = kp + (size_t)NROWS * NM;
    int* mflag = (int*)(vp + (size_t)NROWS * NM);

    detect_mask_fmt<<<1, 256, 0, stream>>>((const unsigned int*)nmask, mflag);
    proj_qkv<<<NB*NA, 256, 0, stream>>>(x, Wq, bq, Wk, bk, Wv, bv, qp, kp, vp);
    attn_kernel<<<NB*NA*NH, 128, 0, stream>>>(qp, kp, vp, gb, nidx, nmask, mflag,
                                              attn, /*ctx aliases out*/ out);
    out_proj<<<NB*NA, 256, 0, stream>>>(out, Wo, bo, out);
}

// Round 3
// 374.788 us; speedup vs baseline: 2.1455x; 1.0395x over previous
//
#include <hip/hip_runtime.h>
#include <math.h>

// FutureFutureCrossAttention — MI355X, round 3.
// Shapes: B=8 A=64 K=16 L=30 D=M=128 H=8 hd=16.
//  - prep_kernel: W^T -> bf16 hi/lo in ws (4 matrices), + mask-fmt detect + bias pack.
//  - proj_mfma:  Y = X@W + b via mfma_f32_16x16x32_bf16, 3-product hi/lo split
//                (f32-grade accuracy). No LDS; B-frags from pre-transposed ws.
//                Also used in-place for the output projection.
//  - attn_kernel: round-2 MFMA attention + vectorized (dwordx4) attn stores via
//                wave-private f32 LDS chunk buffer.
// Verified fragment layouts (learn_hip m89): A[m=lane&15][k=quad*8+j],
// C/D col=lane&15, row=quad*4+reg.

#define NB 8
#define NA 64
#define NK 16
#define NL 30
#define ND 128
#define NM 128
#define NH 8
#define NHD 16
#define NKK (NK*NL)          // 480
#define FSCALE 0.25f         // 16^-0.5
#define NROWS (NB*NA*NL)     // 15360

typedef __attribute__((ext_vector_type(8))) short bf16x8;
typedef __attribute__((ext_vector_type(4))) float f32x4;

__device__ __forceinline__ unsigned short bf16r(float x) {
    unsigned u = __float_as_uint(x);
    return (unsigned short)((u + 0x7fffu + ((u >> 16) & 1u)) >> 16);
}
__device__ __forceinline__ float bf16tof(unsigned short h) {
    return __uint_as_float((unsigned)h << 16);
}

// ---------------------------------------------------------------------------
// prep: blocks 0..7 = (matrix m = bid>>1, k-half = bid&1) transpose W -> bf16
// hi/lo layout Wt[m][n][k]; block 8 = mask-format detect + bias pack.
__global__ __launch_bounds__(256) void prep_kernel(
    const float* __restrict__ Wq, const float* __restrict__ Wk,
    const float* __restrict__ Wv, const float* __restrict__ Wo,
    const float* __restrict__ bq, const float* __restrict__ bk,
    const float* __restrict__ bv, const float* __restrict__ bo,
    const unsigned int* __restrict__ nmask_u, int* __restrict__ mflag,
    short* __restrict__ WtH, short* __restrict__ WtL, float* __restrict__ bias_ws)
{
    const int t = threadIdx.x;
    if (blockIdx.x == 8) {
        __shared__ int not_i32, not_f32;
        if (t == 0) { not_i32 = 0; not_f32 = 0; }
        __syncthreads();
        for (int i = t; i < 2048; i += 256) {
            unsigned u = nmask_u[i];
            if (u > 1u) not_i32 = 1;                       // benign race
            if (u != 0u && u != 0x3F800000u) not_f32 = 1;
        }
        __syncthreads();
        if (t == 0) *mflag = (!not_i32) ? 0 : ((!not_f32) ? 1 : 2);
        if (t < 128) {
            bias_ws[t]       = bq[t];
            bias_ws[128 + t] = bk[t];
            bias_ws[256 + t] = bv[t];
            bias_ws[384 + t] = bo[t];
        }
        return;
    }
    const int m = blockIdx.x >> 1, half = blockIdx.x & 1, d0 = half * 64;
    const float* W = (m == 0) ? Wq : (m == 1) ? Wk : (m == 2) ? Wv : Wo;
    __shared__ __align__(16) float xs[64][132];            // pad 4 -> conflict-free
    for (int i = t; i < 2048; i += 256) {                  // 64x128 f32, float4 loads
        const int dd = i >> 5, j4 = (i & 31) * 4;
        *(float4*)&xs[dd][j4] = *(const float4*)(W + (size_t)(d0 + dd) * NM + j4);
    }
    __syncthreads();
    const int n = t >> 1, hs = t & 1;                      // col n, k-subhalf hs
    unsigned short hb[32], lb[32];
    #pragma unroll
    for (int s = 0; s < 32; ++s) {
        float v = xs[hs*32 + s][n];                        // W[d0+hs*32+s][n]
        unsigned short h = bf16r(v);
        hb[s] = h;
        lb[s] = bf16r(v - bf16tof(h));
    }
    const size_t base = (size_t)m * 16384 + (size_t)n * 128 + d0 + hs * 32;
    #pragma unroll
    for (int g = 0; g < 8; ++g) {
        unsigned long long ph =
              (unsigned long long)hb[4*g]
            | ((unsigned long long)hb[4*g+1] << 16)
            | ((unsigned long long)hb[4*g+2] << 32)
            | ((unsigned long long)hb[4*g+3] << 48);
        unsigned long long pl =
              (unsigned long long)lb[4*g]
            | ((unsigned long long)lb[4*g+1] << 16)
            | ((unsigned long long)lb[4*g+2] << 32)
            | ((unsigned long long)lb[4*g+3] << 48);
        *(unsigned long long*)(WtH + base + g*4) = ph;
        *(unsigned long long*)(WtL + base + g*4) = pl;
    }
}

// ---------------------------------------------------------------------------
// MFMA projection: Y[m] = X @ W[mat_off+m] + b[mat_off+m].
// grid (NROWS/64, nmat); 256 thr = 4 waves; wave w owns rows rt*64+w*16..+15.
// 3-product hi/lo split => ~f32 accuracy. No LDS. NOTE: X/Y may alias (output
// projection runs in place): per-wave, all A loads complete (consumed by the
// first MFMA chain) before any store issues; waves/blocks touch disjoint rows.
__global__ __launch_bounds__(256) void proj_mfma(
    const float* X,
    const short* __restrict__ WtH, const short* __restrict__ WtL,
    const float* __restrict__ bias_ws,
    float* Y, int mat_off)
{
    const int m    = blockIdx.y;
    const int mi   = mat_off + m;
    const int rt   = blockIdx.x;
    const int t    = threadIdx.x;
    const int lane = t & 63, w = t >> 6;
    const int n    = lane & 15, quad = lane >> 4;

    const short* wh = WtH + (size_t)mi * 16384;
    const short* wl = WtL + (size_t)mi * 16384;

    // A fragments: row = rt*64 + w*16 + n (A[m=lane&15][k=quad*8+j])
    const int arow = rt*64 + w*16 + n;
    const float* xr = X + (size_t)arow * ND;
    bf16x8 Ah[4], Al[4];
    #pragma unroll
    for (int ks = 0; ks < 4; ++ks) {
        float4 x0 = *(const float4*)(xr + ks*32 + quad*8);
        float4 x1 = *(const float4*)(xr + ks*32 + quad*8 + 4);
        float xv[8] = {x0.x,x0.y,x0.z,x0.w,x1.x,x1.y,x1.z,x1.w};
        #pragma unroll
        for (int j = 0; j < 8; ++j) {
            unsigned short h = bf16r(xv[j]);
            Ah[ks][j] = (short)h;
            Al[ks][j] = (short)bf16r(xv[j] - bf16tof(h));
        }
    }

    float* ym = Y + (size_t)m * NROWS * NM;
    #pragma unroll
    for (int nt = 0; nt < 8; ++nt) {
        f32x4 acc = {0.f, 0.f, 0.f, 0.f};
        #pragma unroll
        for (int ks = 0; ks < 4; ++ks) {
            const size_t boff = (size_t)(nt*16 + n) * 128 + ks*32 + quad*8;
            bf16x8 bh = *(const bf16x8*)(wh + boff);
            bf16x8 bl = *(const bf16x8*)(wl + boff);
            acc = __builtin_amdgcn_mfma_f32_16x16x32_bf16(Ah[ks], bh, acc, 0, 0, 0);
            acc = __builtin_amdgcn_mfma_f32_16x16x32_bf16(Al[ks], bh, acc, 0, 0, 0);
            acc = __builtin_amdgcn_mfma_f32_16x16x32_bf16(Ah[ks], bl, acc, 0, 0, 0);
        }
        const float bn = bias_ws[mi*128 + nt*16 + n];
        #pragma unroll
        for (int r = 0; r < 4; ++r)
            ym[(size_t)(rt*64 + w*16 + quad*4 + r) * NM + nt*16 + n] = acc[r] + bn;
    }
}

// ---------------------------------------------------------------------------
// MFMA attention. Block = (ba, h), 128 threads = 2 waves; wave w owns q rows
// w*16 .. w*16+15 (rows 30,31 zero-padded, stores masked).
__global__ __launch_bounds__(128, 2) void attn_kernel(
    const float* __restrict__ qp, const float* __restrict__ kp, const float* __restrict__ vp,
    const float* __restrict__ geom_bias, const int* __restrict__ nidx,
    const void* __restrict__ nmask, const int* __restrict__ mask_fmt,
    float* __restrict__ attn_out, float* __restrict__ ctx_out)
{
    __shared__ __align__(16) short Kbf[NKK][16];   // gathered K bf16 [kk][hd]   15360 B
    __shared__ __align__(16) short Vt[16][488];    // gathered V^T bf16 [hd][kk] 15616 B
    __shared__ __align__(16) short pbuf[2][16][40];// per-wave P chunk bf16       2560 B
    __shared__ __align__(16) float pf[2][16][34];  // per-wave P chunk f32        4352 B
    __shared__ float bias_ext[NKK];                //                             1920 B
    __shared__ float biasm[NK];
    __shared__ int   idx_s[NK];

    const int t    = threadIdx.x;
    const int blk  = blockIdx.x;          // ba*8 + h
    const int h    = blk & 7;
    const int ba   = blk >> 3;
    const int b    = ba >> 6;             // A = 64
    const int lane = t & 63;
    const int w    = t >> 6;              // wave id = q-tile id
    const int n    = lane & 15;
    const int quad = lane >> 4;

    if (t < NK) {
        idx_s[t] = nidx[ba*NK + t];
        const int fmt = *mask_fmt;
        bool mv;
        if (fmt == 0)      mv = ((const int*)nmask)[ba*NK + t] != 0;
        else if (fmt == 1) mv = ((const float*)nmask)[ba*NK + t] != 0.0f;
        else               mv = ((const unsigned char*)nmask)[ba*NK + t] != 0;
        biasm[t] = mv ? geom_bias[ba*NK + t] : -INFINITY;
    }
    __syncthreads();   // idx_s / biasm ready

    // ---- stage gathered K (bf16) and V^T (bf16), fill bias_ext ----
    for (int i = t; i < NKK*4; i += 128) {
        const int kk = i >> 2, p = i & 3;
        const int kn = kk / NL, l = kk - kn*NL;
        const size_t off = ((size_t)(b*NA + idx_s[kn])*NL + l)*NM + h*NHD + p*4;
        float4 kv = *(const float4*)(kp + off);
        unsigned long long pk =
              (unsigned long long)bf16r(kv.x)
            | ((unsigned long long)bf16r(kv.y) << 16)
            | ((unsigned long long)bf16r(kv.z) << 32)
            | ((unsigned long long)bf16r(kv.w) << 48);
        *(unsigned long long*)&Kbf[kk][p*4] = pk;
        float4 vv = *(const float4*)(vp + off);
        Vt[p*4+0][kk] = (short)bf16r(vv.x);
        Vt[p*4+1][kk] = (short)bf16r(vv.y);
        Vt[p*4+2][kk] = (short)bf16r(vv.z);
        Vt[p*4+3][kk] = (short)bf16r(vv.w);
    }
    for (int i = t; i < NKK; i += 128) bias_ext[i] = biasm[i / NL];

    // ---- Q A-fragments: hi/lo bf16 split, SCALE folded in ----
    bf16x8 a_hi, a_lo;
    #pragma unroll
    for (int j = 0; j < 8; ++j) { a_hi[j] = 0; a_lo[j] = 0; }
    const int qrow = w*16 + n;
    if (quad < 2 && qrow < NL) {
        const float* qb = qp + ((size_t)ba*NL + qrow)*NM + h*NHD + quad*8;
        float4 x0 = *(const float4*)(qb);
        float4 x1 = *(const float4*)(qb + 4);
        float xv[8] = {x0.x,x0.y,x0.z,x0.w,x1.x,x1.y,x1.z,x1.w};
        #pragma unroll
        for (int j = 0; j < 8; ++j) {
            float x = xv[j] * FSCALE;
            unsigned short hbv = bf16r(x);
            a_hi[j] = (short)hbv;
            a_lo[j] = (short)bf16r(x - bf16tof(hbv));
        }
    }
    __syncthreads();   // Kbf / Vt / bias_ext ready

    // ---- QK^T: 30 tiles of 16 kk; scores in C layout (row=quad*4+r, col=n) ----
    float s[NL][4];
    #pragma unroll
    for (int tt = 0; tt < NL; ++tt) {
        bf16x8 bfrag;
        #pragma unroll
        for (int j = 0; j < 8; ++j) bfrag[j] = 0;
        if (quad < 2)
            bfrag = *(const bf16x8*)&Kbf[tt*16 + n][quad*8];
        f32x4 acc = {0.f, 0.f, 0.f, 0.f};
        acc = __builtin_amdgcn_mfma_f32_16x16x32_bf16(a_hi, bfrag, acc, 0, 0, 0);
        acc = __builtin_amdgcn_mfma_f32_16x16x32_bf16(a_lo, bfrag, acc, 0, 0, 0);
        const float bv = bias_ext[tt*16 + n];
        s[tt][0] = acc[0] + bv;
        s[tt][1] = acc[1] + bv;
        s[tt][2] = acc[2] + bv;
        s[tt][3] = acc[3] + bv;
    }

    // ---- softmax along kk ----
    #pragma unroll
    for (int r = 0; r < 4; ++r) {
        float m = -INFINITY;
        #pragma unroll
        for (int tt = 0; tt < NL; ++tt) m = fmaxf(m, s[tt][r]);
        m = fmaxf(m, __shfl_xor(m, 1));
        m = fmaxf(m, __shfl_xor(m, 2));
        m = fmaxf(m, __shfl_xor(m, 4));
        m = fmaxf(m, __shfl_xor(m, 8));
        const bool ok = (m > -INFINITY);
        float sum = 0.f;
        #pragma unroll
        for (int tt = 0; tt < NL; ++tt) {
            float p = ok ? __expf(s[tt][r] - m) : 0.f;
            s[tt][r] = p;
            sum += p;
        }
        sum += __shfl_xor(sum, 1);
        sum += __shfl_xor(sum, 2);
        sum += __shfl_xor(sum, 4);
        sum += __shfl_xor(sum, 8);
        const float inv = (sum > 0.f) ? 1.f / sum : 0.f;
        #pragma unroll
        for (int tt = 0; tt < NL; ++tt) s[tt][r] *= inv;
    }

    // ---- PV + vectorized attn store, per 32-kk chunk ----
    const size_t abase = (size_t)blk * NL * NKK;
    const int rr = lane >> 2, seg = lane & 3;   // store mapping: row rr, 8-col seg
    const int qr_st = w*16 + rr;
    f32x4 ctx = {0.f, 0.f, 0.f, 0.f};
    #pragma unroll
    for (int c = 0; c < 15; ++c) {
        #pragma unroll
        for (int r = 0; r < 4; ++r) {
            const float p0 = s[2*c][r], p1 = s[2*c + 1][r];
            pbuf[w][quad*4 + r][n]      = (short)bf16r(p0);
            pbuf[w][quad*4 + r][16 + n] = (short)bf16r(p1);
            pf[w][quad*4 + r][n]        = p0;
            pf[w][quad*4 + r][16 + n]   = p1;
        }
        // same-wave ds_write -> ds_read: LDS pipe is in-order per wave
        bf16x8 pa = *(const bf16x8*)&pbuf[w][n][quad*8];          // A[m=n][k=quad*8+j]
        bf16x8 vb = *(const bf16x8*)&Vt[n][c*32 + quad*8];        // B[k][n=d]
        ctx = __builtin_amdgcn_mfma_f32_16x16x32_bf16(pa, vb, ctx, 0, 0, 0);
        if (qr_st < NL) {
            float2 u0 = *(const float2*)&pf[w][rr][seg*8 + 0];
            float2 u1 = *(const float2*)&pf[w][rr][seg*8 + 2];
            float2 u2 = *(const float2*)&pf[w][rr][seg*8 + 4];
            float2 u3 = *(const float2*)&pf[w][rr][seg*8 + 6];
            float4 o0 = make_float4(u0.x, u0.y, u1.x, u1.y);
            float4 o1 = make_float4(u2.x, u2.y, u3.x, u3.y);
            float* ap = attn_out + abase + (size_t)qr_st*NKK + c*32 + seg*8;
            *(float4*)ap       = o0;
            *(float4*)(ap + 4) = o1;
        }
    }

    // ---- ctx out: row=quad*4+r (q), col=n (d) ----
    #pragma unroll
    for (int r = 0; r < 4; ++r) {
        const int qr = w*16 + quad*4 + r;
        if (qr < NL)
            ctx_out[((size_t)ba*NL + qr)*NM + h*NHD + n] = ctx[r];
    }
}

// ---------------------------------------------------------------------------
extern "C" void kernel_launch(void* const* d_in, const int* in_sizes, int n_in,
                              void* d_out, int out_size, void* d_ws, size_t ws_size,
                              hipStream_t stream)
{
    const float* x    = (const float*)d_in[0];
    const float* gb   = (const float*)d_in[1];
    const float* Wq   = (const float*)d_in[2];
    const float* bq   = (const float*)d_in[3];
    const float* Wk   = (const float*)d_in[4];
    const float* bk   = (const float*)d_in[5];
    const float* Wv   = (const float*)d_in[6];
    const float* bv   = (const float*)d_in[7];
    const float* Wo   = (const float*)d_in[8];
    const float* bo   = (const float*)d_in[9];
    const int*   nidx = (const int*)d_in[10];
    const void*  nmask= d_in[11];

    float* out  = (float*)d_out;                       // [15360, 128]
    float* attn = out + (size_t)NROWS * NM;            // [B,A,H,L,K,L] flat

    float* qp = (float*)d_ws;                          // 3 x 7.86 MB (contiguous)
    float* kp = qp + (size_t)NROWS * NM;
    float* vp = kp + (size_t)NROWS * NM;
    int*   mflag   = (int*)(vp + (size_t)NROWS * NM);
    float* bias_ws = (float*)(mflag + 4);              // [4][128]
    short* WtH     = (short*)(bias_ws + 512);          // [4][128][128] bf16 hi
    short* WtL     = WtH + 4 * 16384;                  // [4][128][128] bf16 lo

    prep_kernel<<<9, 256, 0, stream>>>(Wq, Wk, Wv, Wo, bq, bk, bv, bo,
                                       (const unsigned int*)nmask, mflag,
                                       WtH, WtL, bias_ws);
    dim3 gproj(NROWS/64, 3);
    proj_mfma<<<gproj, 256, 0, stream>>>(x, WtH, WtL, bias_ws, qp, 0);
    attn_kernel<<<NB*NA*NH, 128, 0, stream>>>(qp, kp, vp, gb, nidx, nmask, mflag,
                                              attn, /*ctx aliases out*/ out);
    dim3 gout(NROWS/64, 1);
    proj_mfma<<<gout, 256, 0, stream>>>(out, WtH, WtL, bias_ws, out, 3);
}

// Round 4
// 367.221 us; speedup vs baseline: 2.1897x; 1.0206x over previous
//
#include <hip/hip_runtime.h>
#include <math.h>

// FutureFutureCrossAttention — MI355X, round 4.
// Shapes: B=8 A=64 K=16 L=30 D=M=128 H=8 hd=16.
// Round-4 changes vs round 3:
//  - proj_mfma: registers tamed — nt loop no longer fully unrolled (was hoisting
//    ~64 in-flight B-frag loads -> spill risk), __launch_bounds__(256,3) caps
//    VGPR at 168, Wt base pointers pre-offset.
//  - attn_kernel: pf chunk buffer stride 34 -> 36 floats (16B-aligned rows) so
//    attn-store reads are two ds_read_b128; LDS still <= 40960 B -> 4 blocks/CU.
// Verified fragment layouts (learn_hip m89): A[m=lane&15][k=quad*8+j],
// C/D col=lane&15, row=quad*4+reg.

#define NB 8
#define NA 64
#define NK 16
#define NL 30
#define ND 128
#define NM 128
#define NH 8
#define NHD 16
#define NKK (NK*NL)          // 480
#define FSCALE 0.25f         // 16^-0.5
#define NROWS (NB*NA*NL)     // 15360

typedef __attribute__((ext_vector_type(8))) short bf16x8;
typedef __attribute__((ext_vector_type(4))) float f32x4;

__device__ __forceinline__ unsigned short bf16r(float x) {
    unsigned u = __float_as_uint(x);
    return (unsigned short)((u + 0x7fffu + ((u >> 16) & 1u)) >> 16);
}
__device__ __forceinline__ float bf16tof(unsigned short h) {
    return __uint_as_float((unsigned)h << 16);
}

// ---------------------------------------------------------------------------
// prep: blocks 0..7 = (matrix m = bid>>1, k-half = bid&1) transpose W -> bf16
// hi/lo layout Wt[m][n][k]; block 8 = mask-format detect + bias pack.
__global__ __launch_bounds__(256) void prep_kernel(
    const float* __restrict__ Wq, const float* __restrict__ Wk,
    const float* __restrict__ Wv, const float* __restrict__ Wo,
    const float* __restrict__ bq, const float* __restrict__ bk,
    const float* __restrict__ bv, const float* __restrict__ bo,
    const unsigned int* __restrict__ nmask_u, int* __restrict__ mflag,
    short* __restrict__ WtH, short* __restrict__ WtL, float* __restrict__ bias_ws)
{
    const int t = threadIdx.x;
    if (blockIdx.x == 8) {
        __shared__ int not_i32, not_f32;
        if (t == 0) { not_i32 = 0; not_f32 = 0; }
        __syncthreads();
        for (int i = t; i < 2048; i += 256) {
            unsigned u = nmask_u[i];
            if (u > 1u) not_i32 = 1;                       // benign race
            if (u != 0u && u != 0x3F800000u) not_f32 = 1;
        }
        __syncthreads();
        if (t == 0) *mflag = (!not_i32) ? 0 : ((!not_f32) ? 1 : 2);
        if (t < 128) {
            bias_ws[t]       = bq[t];
            bias_ws[128 + t] = bk[t];
            bias_ws[256 + t] = bv[t];
            bias_ws[384 + t] = bo[t];
        }
        return;
    }
    const int m = blockIdx.x >> 1, half = blockIdx.x & 1, d0 = half * 64;
    const float* W = (m == 0) ? Wq : (m == 1) ? Wk : (m == 2) ? Wv : Wo;
    __shared__ __align__(16) float xs[64][132];            // pad 4 -> conflict-free
    for (int i = t; i < 2048; i += 256) {                  // 64x128 f32, float4 loads
        const int dd = i >> 5, j4 = (i & 31) * 4;
        *(float4*)&xs[dd][j4] = *(const float4*)(W + (size_t)(d0 + dd) * NM + j4);
    }
    __syncthreads();
    const int n = t >> 1, hs = t & 1;                      // col n, k-subhalf hs
    unsigned short hb[32], lb[32];
    #pragma unroll
    for (int s = 0; s < 32; ++s) {
        float v = xs[hs*32 + s][n];                        // W[d0+hs*32+s][n]
        unsigned short h = bf16r(v);
        hb[s] = h;
        lb[s] = bf16r(v - bf16tof(h));
    }
    const size_t base = (size_t)m * 16384 + (size_t)n * 128 + d0 + hs * 32;
    #pragma unroll
    for (int g = 0; g < 8; ++g) {
        unsigned long long ph =
              (unsigned long long)hb[4*g]
            | ((unsigned long long)hb[4*g+1] << 16)
            | ((unsigned long long)hb[4*g+2] << 32)
            | ((unsigned long long)hb[4*g+3] << 48);
        unsigned long long pl =
              (unsigned long long)lb[4*g]
            | ((unsigned long long)lb[4*g+1] << 16)
            | ((unsigned long long)lb[4*g+2] << 32)
            | ((unsigned long long)lb[4*g+3] << 48);
        *(unsigned long long*)(WtH + base + g*4) = ph;
        *(unsigned long long*)(WtL + base + g*4) = pl;
    }
}

// ---------------------------------------------------------------------------
// MFMA projection: Y[m] = X @ W[mat_off+m] + b[mat_off+m].
// grid (NROWS/64, nmat); 256 thr = 4 waves; wave w owns rows rt*64+w*16..+15.
// 3-product hi/lo split => ~f32 accuracy. No LDS. NOTE: X/Y may alias (output
// projection runs in place): per-wave, all A loads are issued before any store;
// waves/blocks touch disjoint 16-row groups.
// __launch_bounds__(256,3): cap VGPR<=168 so the compiler cannot hoist all 64
// B-frag loads (round-3 full unroll risked scratch spills).
__global__ __launch_bounds__(256, 3) void proj_mfma(
    const float* X,
    const short* __restrict__ WtH, const short* __restrict__ WtL,
    const float* __restrict__ bias_ws,
    float* Y, int mat_off)
{
    const int m    = blockIdx.y;
    const int mi   = mat_off + m;
    const int rt   = blockIdx.x;
    const int t    = threadIdx.x;
    const int lane = t & 63, w = t >> 6;
    const int n    = lane & 15, quad = lane >> 4;

    const short* wh = WtH + (size_t)mi * 16384 + (size_t)n * 128 + quad * 8;
    const short* wl = WtL + (size_t)mi * 16384 + (size_t)n * 128 + quad * 8;

    // A fragments: row = rt*64 + w*16 + n (A[m=lane&15][k=quad*8+j])
    const int arow = rt*64 + w*16 + n;
    const float* xr = X + (size_t)arow * ND + quad*8;
    bf16x8 Ah[4], Al[4];
    #pragma unroll
    for (int ks = 0; ks < 4; ++ks) {
        float4 x0 = *(const float4*)(xr + ks*32);
        float4 x1 = *(const float4*)(xr + ks*32 + 4);
        float xv[8] = {x0.x,x0.y,x0.z,x0.w,x1.x,x1.y,x1.z,x1.w};
        #pragma unroll
        for (int j = 0; j < 8; ++j) {
            unsigned short h = bf16r(xv[j]);
            Ah[ks][j] = (short)h;
            Al[ks][j] = (short)bf16r(xv[j] - bf16tof(h));
        }
    }

    float* yb = Y + (size_t)m * NROWS * NM
                  + (size_t)(rt*64 + w*16 + quad*4) * NM + n;
    #pragma unroll 2
    for (int nt = 0; nt < 8; ++nt) {
        f32x4 acc = {0.f, 0.f, 0.f, 0.f};
        #pragma unroll
        for (int ks = 0; ks < 4; ++ks) {
            bf16x8 bh = *(const bf16x8*)(wh + nt*2048 + ks*32);
            bf16x8 bl = *(const bf16x8*)(wl + nt*2048 + ks*32);
            acc = __builtin_amdgcn_mfma_f32_16x16x32_bf16(Ah[ks], bh, acc, 0, 0, 0);
            acc = __builtin_amdgcn_mfma_f32_16x16x32_bf16(Al[ks], bh, acc, 0, 0, 0);
            acc = __builtin_amdgcn_mfma_f32_16x16x32_bf16(Ah[ks], bl, acc, 0, 0, 0);
        }
        const float bn = bias_ws[mi*128 + nt*16 + n];
        #pragma unroll
        for (int r = 0; r < 4; ++r)
            yb[(size_t)r * NM + nt*16] = acc[r] + bn;
    }
}

// ---------------------------------------------------------------------------
// MFMA attention. Block = (ba, h), 128 threads = 2 waves; wave w owns q rows
// w*16 .. w*16+15 (rows 30,31 zero-padded, stores masked).
__global__ __launch_bounds__(128, 2) void attn_kernel(
    const float* __restrict__ qp, const float* __restrict__ kp, const float* __restrict__ vp,
    const float* __restrict__ geom_bias, const int* __restrict__ nidx,
    const void* __restrict__ nmask, const int* __restrict__ mask_fmt,
    float* __restrict__ attn_out, float* __restrict__ ctx_out)
{
    __shared__ __align__(16) short Kbf[NKK][16];   // gathered K bf16 [kk][hd]   15360 B
    __shared__ __align__(16) short Vt[16][488];    // gathered V^T bf16 [hd][kk] 15616 B
    __shared__ __align__(16) short pbuf[2][16][40];// per-wave P chunk bf16       2560 B
    __shared__ __align__(16) float pf[2][16][36];  // per-wave P chunk f32        4608 B (stride 36 -> b128-aligned rows)
    __shared__ float bias_ext[NKK];                //                             1920 B
    __shared__ float biasm[NK];
    __shared__ int   idx_s[NK];

    const int t    = threadIdx.x;
    const int blk  = blockIdx.x;          // ba*8 + h
    const int h    = blk & 7;
    const int ba   = blk >> 3;
    const int b    = ba >> 6;             // A = 64
    const int lane = t & 63;
    const int w    = t >> 6;              // wave id = q-tile id
    const int n    = lane & 15;
    const int quad = lane >> 4;

    if (t < NK) {
        idx_s[t] = nidx[ba*NK + t];
        const int fmt = *mask_fmt;
        bool mv;
        if (fmt == 0)      mv = ((const int*)nmask)[ba*NK + t] != 0;
        else if (fmt == 1) mv = ((const float*)nmask)[ba*NK + t] != 0.0f;
        else               mv = ((const unsigned char*)nmask)[ba*NK + t] != 0;
        biasm[t] = mv ? geom_bias[ba*NK + t] : -INFINITY;
    }
    __syncthreads();   // idx_s / biasm ready

    // ---- stage gathered K (bf16) and V^T (bf16), fill bias_ext ----
    for (int i = t; i < NKK*4; i += 128) {
        const int kk = i >> 2, p = i & 3;
        const int kn = kk / NL, l = kk - kn*NL;
        const size_t off = ((size_t)(b*NA + idx_s[kn])*NL + l)*NM + h*NHD + p*4;
        float4 kv = *(const float4*)(kp + off);
        unsigned long long pk =
              (unsigned long long)bf16r(kv.x)
            | ((unsigned long long)bf16r(kv.y) << 16)
            | ((unsigned long long)bf16r(kv.z) << 32)
            | ((unsigned long long)bf16r(kv.w) << 48);
        *(unsigned long long*)&Kbf[kk][p*4] = pk;
        float4 vv = *(const float4*)(vp + off);
        Vt[p*4+0][kk] = (short)bf16r(vv.x);
        Vt[p*4+1][kk] = (short)bf16r(vv.y);
        Vt[p*4+2][kk] = (short)bf16r(vv.z);
        Vt[p*4+3][kk] = (short)bf16r(vv.w);
    }
    for (int i = t; i < NKK; i += 128) bias_ext[i] = biasm[i / NL];

    // ---- Q A-fragments: hi/lo bf16 split, SCALE folded in ----
    bf16x8 a_hi, a_lo;
    #pragma unroll
    for (int j = 0; j < 8; ++j) { a_hi[j] = 0; a_lo[j] = 0; }
    const int qrow = w*16 + n;
    if (quad < 2 && qrow < NL) {
        const float* qb = qp + ((size_t)ba*NL + qrow)*NM + h*NHD + quad*8;
        float4 x0 = *(const float4*)(qb);
        float4 x1 = *(const float4*)(qb + 4);
        float xv[8] = {x0.x,x0.y,x0.z,x0.w,x1.x,x1.y,x1.z,x1.w};
        #pragma unroll
        for (int j = 0; j < 8; ++j) {
            float x = xv[j] * FSCALE;
            unsigned short hbv = bf16r(x);
            a_hi[j] = (short)hbv;
            a_lo[j] = (short)bf16r(x - bf16tof(hbv));
        }
    }
    __syncthreads();   // Kbf / Vt / bias_ext ready

    // ---- QK^T: 30 tiles of 16 kk; scores in C layout (row=quad*4+r, col=n) ----
    float s[NL][4];
    #pragma unroll
    for (int tt = 0; tt < NL; ++tt) {
        bf16x8 bfrag;
        #pragma unroll
        for (int j = 0; j < 8; ++j) bfrag[j] = 0;
        if (quad < 2)
            bfrag = *(const bf16x8*)&Kbf[tt*16 + n][quad*8];
        f32x4 acc = {0.f, 0.f, 0.f, 0.f};
        acc = __builtin_amdgcn_mfma_f32_16x16x32_bf16(a_hi, bfrag, acc, 0, 0, 0);
        acc = __builtin_amdgcn_mfma_f32_16x16x32_bf16(a_lo, bfrag, acc, 0, 0, 0);
        const float bv = bias_ext[tt*16 + n];
        s[tt][0] = acc[0] + bv;
        s[tt][1] = acc[1] + bv;
        s[tt][2] = acc[2] + bv;
        s[tt][3] = acc[3] + bv;
    }

    // ---- softmax along kk ----
    #pragma unroll
    for (int r = 0; r < 4; ++r) {
        float m = -INFINITY;
        #pragma unroll
        for (int tt = 0; tt < NL; ++tt) m = fmaxf(m, s[tt][r]);
        m = fmaxf(m, __shfl_xor(m, 1));
        m = fmaxf(m, __shfl_xor(m, 2));
        m = fmaxf(m, __shfl_xor(m, 4));
        m = fmaxf(m, __shfl_xor(m, 8));
        const bool ok = (m > -INFINITY);
        float sum = 0.f;
        #pragma unroll
        for (int tt = 0; tt < NL; ++tt) {
            float p = ok ? __expf(s[tt][r] - m) : 0.f;
            s[tt][r] = p;
            sum += p;
        }
        sum += __shfl_xor(sum, 1);
        sum += __shfl_xor(sum, 2);
        sum += __shfl_xor(sum, 4);
        sum += __shfl_xor(sum, 8);
        const float inv = (sum > 0.f) ? 1.f / sum : 0.f;
        #pragma unroll
        for (int tt = 0; tt < NL; ++tt) s[tt][r] *= inv;
    }

    // ---- PV + vectorized attn store, per 32-kk chunk ----
    const size_t abase = (size_t)blk * NL * NKK;
    const int rr = lane >> 2, seg = lane & 3;   // store mapping: row rr, 8-col seg
    const int qr_st = w*16 + rr;
    f32x4 ctx = {0.f, 0.f, 0.f, 0.f};
    #pragma unroll
    for (int c = 0; c < 15; ++c) {
        #pragma unroll
        for (int r = 0; r < 4; ++r) {
            const float p0 = s[2*c][r], p1 = s[2*c + 1][r];
            pbuf[w][quad*4 + r][n]      = (short)bf16r(p0);
            pbuf[w][quad*4 + r][16 + n] = (short)bf16r(p1);
            pf[w][quad*4 + r][n]        = p0;
            pf[w][quad*4 + r][16 + n]   = p1;
        }
        // same-wave ds_write -> ds_read: LDS pipe is in-order per wave
        bf16x8 pa = *(const bf16x8*)&pbuf[w][n][quad*8];          // A[m=n][k=quad*8+j]
        bf16x8 vb = *(const bf16x8*)&Vt[n][c*32 + quad*8];        // B[k][n=d]
        ctx = __builtin_amdgcn_mfma_f32_16x16x32_bf16(pa, vb, ctx, 0, 0, 0);
        if (qr_st < NL) {
            float4 o0 = *(const float4*)&pf[w][rr][seg*8 + 0];    // ds_read_b128
            float4 o1 = *(const float4*)&pf[w][rr][seg*8 + 4];
            float* ap = attn_out + abase + (size_t)qr_st*NKK + c*32 + seg*8;
            *(float4*)ap       = o0;
            *(float4*)(ap + 4) = o1;
        }
    }

    // ---- ctx out: row=quad*4+r (q), col=n (d) ----
    #pragma unroll
    for (int r = 0; r < 4; ++r) {
        const int qr = w*16 + quad*4 + r;
        if (qr < NL)
            ctx_out[((size_t)ba*NL + qr)*NM + h*NHD + n] = ctx[r];
    }
}

// ---------------------------------------------------------------------------
extern "C" void kernel_launch(void* const* d_in, const int* in_sizes, int n_in,
                              void* d_out, int out_size, void* d_ws, size_t ws_size,
                              hipStream_t stream)
{
    const float* x    = (const float*)d_in[0];
    const float* gb   = (const float*)d_in[1];
    const float* Wq   = (const float*)d_in[2];
    const float* bq   = (const float*)d_in[3];
    const float* Wk   = (const float*)d_in[4];
    const float* bk   = (const float*)d_in[5];
    const float* Wv   = (const float*)d_in[6];
    const float* bv   = (const float*)d_in[7];
    const float* Wo   = (const float*)d_in[8];
    const float* bo   = (const float*)d_in[9];
    const int*   nidx = (const int*)d_in[10];
    const void*  nmask= d_in[11];

    float* out  = (float*)d_out;                       // [15360, 128]
    float* attn = out + (size_t)NROWS * NM;            // [B,A,H,L,K,L] flat

    float* qp = (float*)d_ws;                          // 3 x 7.86 MB (contiguous)
    float* kp = qp + (size_t)NROWS * NM;
    float* vp = kp + (size_t)NROWS * NM;
    int*   mflag   = (int*)(vp + (size_t)NROWS * NM);
    float* bias_ws = (float*)(mflag + 4);              // [4][128]
    short* WtH     = (short*)(bias_ws + 512);          // [4][128][128] bf16 hi
    short* WtL     = WtH + 4 * 16384;                  // [4][128][128] bf16 lo

    prep_kernel<<<9, 256, 0, stream>>>(Wq, Wk, Wv, Wo, bq, bk, bv, bo,
                                       (const unsigned int*)nmask, mflag,
                                       WtH, WtL, bias_ws);
    dim3 gproj(NROWS/64, 3);
    proj_mfma<<<gproj, 256, 0, stream>>>(x, WtH, WtL, bias_ws, qp, 0);
    attn_kernel<<<NB*NA*NH, 128, 0, stream>>>(qp, kp, vp, gb, nidx, nmask, mflag,
                                              attn, /*ctx aliases out*/ out);
    dim3 gout(NROWS/64, 1);
    proj_mfma<<<gout, 256, 0, stream>>>(out, WtH, WtL, bias_ws, out, 3);
}